// Round 4
// baseline (6606.989 us; speedup 1.0000x reference)
//
#include <hip/hip_runtime.h>
#include <math.h>
#include <stdint.h>

#define SEQ 2048
#define HD 512
#define NHD 6
#define VOCAB 32000
#define G3H 1536

typedef __attribute__((ext_vector_type(8))) short bf8_t;
typedef __attribute__((ext_vector_type(4))) float f4_t;

__device__ __forceinline__ short f2bf(float f) {
  union { float f; unsigned u; } x; x.f = f;
  return (short)((x.u + 0x7fffu + ((x.u >> 16) & 1u)) >> 16);
}
__device__ __forceinline__ float bf2f(short b) {
  union { unsigned u; float f; } x; x.u = ((unsigned)(unsigned short)b) << 16;
  return x.f;
}
__device__ __forceinline__ void async16(void* lds, const void* g) {
  __builtin_amdgcn_global_load_lds((__attribute__((address_space(1))) void*)g,
                                   (__attribute__((address_space(3))) void*)lds, 16, 0, 0);
}
__device__ __forceinline__ float fsigmoid(float x) {
  return 1.f / (1.f + __expf(-x));
}
__device__ __forceinline__ float ftanh(float x) {
  return 1.f - 2.f / (__expf(2.f * x) + 1.f);
}

// ---------------- core 128x128 bf16 MFMA tile GEMM (m97 structure) ----------
__device__ __forceinline__ void gemm_core(const short* __restrict__ A,
                                          const short* __restrict__ Bt,
                                          int K, int m0, int n0,
                                          f4_t acc[4][4],
                                          short* As, short* Bs) {
  int tid = threadIdx.x;
  int lane = tid & 63, wave = tid >> 6;
  int wm = (wave >> 1) * 64, wn = (wave & 1) * 64;
  int srow = lane >> 2, scol = (lane & 3) * 8;
  const short* ag0 = A + (long)(m0 + wave * 32 + srow) * K + scol;
  const short* ag1 = ag0 + 16 * (long)K;
  const short* bg0 = Bt + (long)(n0 + wave * 32 + srow) * K + scol;
  const short* bg1 = bg0 + 16 * (long)K;
  short* al0 = As + wave * 1024;
  short* al1 = As + wave * 1024 + 512;
  short* bl0 = Bs + wave * 1024;
  short* bl1 = Bs + wave * 1024 + 512;
  int fr = lane & 15, fq = lane >> 4;
  const short* afp = As + (wm + fr) * 32 + fq * 8;
  const short* bfp = Bs + (wn + fr) * 32 + fq * 8;
#pragma unroll
  for (int i = 0; i < 4; i++)
#pragma unroll
    for (int j = 0; j < 4; j++) { f4_t z = {0.f, 0.f, 0.f, 0.f}; acc[i][j] = z; }

  for (int k0 = 0; k0 < K; k0 += 32) {
    __syncthreads();
    async16(al0, ag0 + k0);
    async16(al1, ag1 + k0);
    async16(bl0, bg0 + k0);
    async16(bl1, bg1 + k0);
    __syncthreads();
    bf8_t af[4], bf[4];
#pragma unroll
    for (int mi = 0; mi < 4; mi++) af[mi] = *(const bf8_t*)(afp + mi * 512);
#pragma unroll
    for (int ni = 0; ni < 4; ni++) bf[ni] = *(const bf8_t*)(bfp + ni * 512);
#pragma unroll
    for (int mi = 0; mi < 4; mi++)
#pragma unroll
      for (int ni = 0; ni < 4; ni++)
        acc[mi][ni] = __builtin_amdgcn_mfma_f32_16x16x32_bf16(af[mi], bf[ni], acc[mi][ni], 0, 0, 0);
  }
}

// ---------------- embedding gather ----------------
__global__ __launch_bounds__(128) void k_embed(const int* __restrict__ tok, const float* __restrict__ emb,
                                               float* __restrict__ xf, short* __restrict__ xb) {
  int s = blockIdx.x;
  int t = tok[s];
  int c = threadIdx.x * 4;
  float4 v = *(const float4*)(emb + (long)t * HD + c);
  *(float4*)(xf + (long)s * HD + c) = v;
  unsigned p0 = ((unsigned)(unsigned short)f2bf(v.y) << 16) | (unsigned short)f2bf(v.x);
  unsigned p1 = ((unsigned)(unsigned short)f2bf(v.w) << 16) | (unsigned short)f2bf(v.z);
  *(uint2*)(xb + (long)s * HD + c) = make_uint2(p0, p1);
}

// ---------------- fp32 -> bf16 transpose (RxC -> CxR) ----------------
__global__ __launch_bounds__(256) void k_transp(const float* __restrict__ src, short* __restrict__ dst,
                                                int R, int C) {
  __shared__ float tile[64][65];
  const float* s = src + (long)blockIdx.z * R * C;
  short* d = dst + (long)blockIdx.z * R * C;
  int bx = blockIdx.x, by = blockIdx.y;
  int tc = threadIdx.x & 63, tr4 = threadIdx.x >> 6;
#pragma unroll
  for (int i = 0; i < 16; i++) {
    int r = tr4 + i * 4;
    tile[r][tc] = s[(long)(by * 64 + r) * C + bx * 64 + tc];
  }
  __syncthreads();
#pragma unroll
  for (int i = 0; i < 16; i++) {
    int r = tr4 + i * 4;
    d[(long)(bx * 64 + r) * R + by * 64 + tc] = f2bf(tile[tc][r]);
  }
}

// ---------------- fp32 -> bf16 convert (no transpose) ----------------
__global__ __launch_bounds__(256) void k_conv(const float* __restrict__ src, short* __restrict__ dst) {
  long i = (long)(blockIdx.x * 256 + threadIdx.x) * 4;
  float4 v = *(const float4*)(src + i);
  unsigned p0 = ((unsigned)(unsigned short)f2bf(v.y) << 16) | (unsigned short)f2bf(v.x);
  unsigned p1 = ((unsigned)(unsigned short)f2bf(v.w) << 16) | (unsigned short)f2bf(v.z);
  *(uint2*)(dst + i) = make_uint2(p0, p1);
}

// ---------------- QKV projections (18 batched GEMMs) ----------------
__global__ __launch_bounds__(256) void k_qkv(const short* __restrict__ xb, const short* __restrict__ wt,
                                             const float* __restrict__ bq, const float* __restrict__ bk,
                                             const float* __restrict__ bv,
                                             short* __restrict__ Qb, short* __restrict__ Kb,
                                             short* __restrict__ Vt) {
  __shared__ short As[4096], Bs[4096];
  int z = blockIdx.z, which = z / 6, h = z % 6;
  int m0 = blockIdx.x * 128, n0 = blockIdx.y * 128;
  f4_t acc[4][4];
  gemm_core(xb, wt + (long)z * HD * HD, HD, m0, n0, acc, As, Bs);
  int lane = threadIdx.x & 63, wave = threadIdx.x >> 6;
  int wm = (wave >> 1) * 64, wn = (wave & 1) * 64;
  int fr = lane & 15, fq = lane >> 4;
  const float* bias = (which == 0) ? bq : (which == 1) ? bk : bv;
  short* qk = (which == 0) ? Qb : Kb;
#pragma unroll
  for (int mi = 0; mi < 4; mi++)
#pragma unroll
    for (int ni = 0; ni < 4; ni++) {
      int n = n0 + wn + ni * 16 + fr;
      float b = bias[h * HD + n];
#pragma unroll
      for (int r = 0; r < 4; r++) {
        int m = m0 + wm + mi * 16 + fq * 4 + r;
        float v = acc[mi][ni][r] + b;
        if (which < 2) qk[(long)h * SEQ * HD + (long)m * HD + n] = f2bf(v);
        else           Vt[(long)h * HD * SEQ + (long)n * SEQ + m] = f2bf(v);
      }
    }
}

// ---------------- scores = Q K^T / sqrt(H) ----------------
__global__ __launch_bounds__(256) void k_scores(const short* __restrict__ Qb, const short* __restrict__ Kb,
                                                short* __restrict__ Sb) {
  __shared__ short As[4096], Bs[4096];
  int h = blockIdx.z;
  int m0 = blockIdx.x * 128, n0 = blockIdx.y * 128;
  f4_t acc[4][4];
  gemm_core(Qb + (long)h * SEQ * HD, Kb + (long)h * SEQ * HD, HD, m0, n0, acc, As, Bs);
  int lane = threadIdx.x & 63, wave = threadIdx.x >> 6;
  int wm = (wave >> 1) * 64, wn = (wave & 1) * 64;
  int fr = lane & 15, fq = lane >> 4;
  const float sc = 0.04419417382415922f;  // 1/sqrt(512)
#pragma unroll
  for (int mi = 0; mi < 4; mi++)
#pragma unroll
    for (int ni = 0; ni < 4; ni++) {
      int n = n0 + wn + ni * 16 + fr;
#pragma unroll
      for (int r = 0; r < 4; r++) {
        int m = m0 + wm + mi * 16 + fq * 4 + r;
        Sb[(long)h * SEQ * SEQ + (long)m * SEQ + n] = f2bf(acc[mi][ni][r] * sc);
      }
    }
}

// ---------------- row softmax (in-place, bf16) ----------------
__global__ __launch_bounds__(256) void k_softmax(short* __restrict__ S) {
  __shared__ float red[4];
  short* p = S + (long)blockIdx.x * SEQ;
  int tid = threadIdx.x, lane = tid & 63, wv = tid >> 6;
  bf8_t raw = *(const bf8_t*)(p + tid * 8);
  float v[8];
#pragma unroll
  for (int i = 0; i < 8; i++) v[i] = bf2f(raw[i]);
  float mx = v[0];
#pragma unroll
  for (int i = 1; i < 8; i++) mx = fmaxf(mx, v[i]);
#pragma unroll
  for (int o = 32; o; o >>= 1) mx = fmaxf(mx, __shfl_xor(mx, o));
  if (lane == 0) red[wv] = mx;
  __syncthreads();
  float M = fmaxf(fmaxf(red[0], red[1]), fmaxf(red[2], red[3]));
  __syncthreads();
  float e[8], s = 0.f;
#pragma unroll
  for (int i = 0; i < 8; i++) { e[i] = expf(v[i] - M); s += e[i]; }
#pragma unroll
  for (int o = 32; o; o >>= 1) s += __shfl_xor(s, o);
  if (lane == 0) red[wv] = s;
  __syncthreads();
  float inv = 1.f / (red[0] + red[1] + red[2] + red[3]);
  bf8_t o8;
#pragma unroll
  for (int i = 0; i < 8; i++) o8[i] = f2bf(e[i] * inv);
  *(bf8_t*)(p + tid * 8) = o8;
}

// ---------------- heads = P V, written into cat layout ----------------
__global__ __launch_bounds__(256) void k_pv(const short* __restrict__ Sb, const short* __restrict__ Vt,
                                            short* __restrict__ cat) {
  __shared__ short As[4096], Bs[4096];
  int h = blockIdx.z;
  int m0 = blockIdx.x * 128, n0 = blockIdx.y * 128;
  f4_t acc[4][4];
  gemm_core(Sb + (long)h * SEQ * SEQ, Vt + (long)h * HD * SEQ, SEQ, m0, n0, acc, As, Bs);
  int lane = threadIdx.x & 63, wave = threadIdx.x >> 6;
  int wm = (wave >> 1) * 64, wn = (wave & 1) * 64;
  int fr = lane & 15, fq = lane >> 4;
#pragma unroll
  for (int mi = 0; mi < 4; mi++)
#pragma unroll
    for (int ni = 0; ni < 4; ni++) {
      int n = n0 + wn + ni * 16 + fr;
#pragma unroll
      for (int r = 0; r < 4; r++) {
        int m = m0 + wm + mi * 16 + fq * 4 + r;
        cat[(long)m * (NHD * HD) + h * HD + n] = f2bf(acc[mi][ni][r]);
      }
    }
}

// ---------------- out proj + residual: y = x + cat@Wo + bo ----------------
__global__ __launch_bounds__(256) void k_oproj(const short* __restrict__ cat, const short* __restrict__ wot,
                                               const float* __restrict__ bo, const float* __restrict__ xf,
                                               float* __restrict__ y) {
  __shared__ short As[4096], Bs[4096];
  int m0 = blockIdx.x * 128, n0 = blockIdx.y * 128;
  f4_t acc[4][4];
  gemm_core(cat, wot, NHD * HD, m0, n0, acc, As, Bs);
  int lane = threadIdx.x & 63, wave = threadIdx.x >> 6;
  int wm = (wave >> 1) * 64, wn = (wave & 1) * 64;
  int fr = lane & 15, fq = lane >> 4;
#pragma unroll
  for (int mi = 0; mi < 4; mi++)
#pragma unroll
    for (int ni = 0; ni < 4; ni++) {
      int n = n0 + wn + ni * 16 + fr;
      float b = bo[n];
#pragma unroll
      for (int r = 0; r < 4; r++) {
        int m = m0 + wm + mi * 16 + fq * 4 + r;
        y[(long)m * HD + n] = acc[mi][ni][r] + b + xf[(long)m * HD + n];
      }
    }
}

// ---------------- LayerNorm ----------------
__global__ __launch_bounds__(256) void k_ln(const float* __restrict__ y, const float* __restrict__ gamma,
                                            const float* __restrict__ beta, short* __restrict__ x2b) {
  __shared__ float red[8];
  int r = blockIdx.x, tid = threadIdx.x, lane = tid & 63, wv = tid >> 6;
  float2 v = *(const float2*)(y + (long)r * HD + tid * 2);
  float s = v.x + v.y, q = v.x * v.x + v.y * v.y;
#pragma unroll
  for (int o = 32; o; o >>= 1) { s += __shfl_xor(s, o); q += __shfl_xor(q, o); }
  if (lane == 0) { red[wv] = s; red[4 + wv] = q; }
  __syncthreads();
  float S = red[0] + red[1] + red[2] + red[3];
  float Q = red[4] + red[5] + red[6] + red[7];
  float mu = S / 512.f, var = Q / 512.f - mu * mu;
  float rs = rsqrtf(var + 1e-5f);
  int c = tid * 2;
  float o0 = (v.x - mu) * rs * gamma[c] + beta[c];
  float o1 = (v.y - mu) * rs * gamma[c + 1] + beta[c + 1];
  unsigned pk = ((unsigned)(unsigned short)f2bf(o1) << 16) | (unsigned short)f2bf(o0);
  *(unsigned*)(x2b + (long)r * HD + c) = pk;
}

// ---------------- gi = x2 @ W_ih^T + b_ih (fp32 out) ----------------
__global__ __launch_bounds__(256) void k_gi(const short* __restrict__ x2b, const short* __restrict__ wihb,
                                            const float* __restrict__ bih, float* __restrict__ gi) {
  __shared__ short As[4096], Bs[4096];
  int m0 = blockIdx.x * 128, n0 = blockIdx.y * 128;
  f4_t acc[4][4];
  gemm_core(x2b, wihb, HD, m0, n0, acc, As, Bs);
  int lane = threadIdx.x & 63, wave = threadIdx.x >> 6;
  int wm = (wave >> 1) * 64, wn = (wave & 1) * 64;
  int fr = lane & 15, fq = lane >> 4;
#pragma unroll
  for (int mi = 0; mi < 4; mi++)
#pragma unroll
    for (int ni = 0; ni < 4; ni++) {
      int n = n0 + wn + ni * 16 + fr;
      float b = bih[n];
#pragma unroll
      for (int r = 0; r < 4; r++) {
        int m = m0 + wm + mi * 16 + fq * 4 + r;
        gi[(long)m * G3H + n] = acc[mi][ni][r] + b;
      }
    }
}

// ---------------- GRU init: pack h0 with tag 0 ----------------
__global__ __launch_bounds__(512) void k_gruinit(const float* __restrict__ h0,
                                                 unsigned long long* __restrict__ hbuf) {
  int i = threadIdx.x;
  hbuf[i] = (unsigned long long)__float_as_uint(h0[i]);  // tag 0 in hi32
  hbuf[512 + i] = 0xFFFFFFFF00000000ULL;
  hbuf[1024 + i] = 0xFFFFFFFF00000000ULL;
}

// ---------------- GRU scan: 32 co-resident blocks, tagged-h exchange -------
// 32 blocks x 576 threads. Waves 0-7 (tid<512): each thread polls exactly ONE
// hbuf slot (pipelined, no sleep), writes h to LDS; wave w computes the
// 6 W_hh rows for elements {16g+2w, 16g+2w+1} with spread-column layout
// (lane l owns columns {l,64+l,...}); lanes 0,1 run the gates. Wave 8 is a
// prefetch helper: stages gi(t+1) into TRIPLE-buffered LDS (a 2-deep rotation
// races with one barrier/step: write of buf b at iter t+1 shares the
// S_t->S_{t+1} window with the read of buf b at iter t — round-3 bug).
__global__ __launch_bounds__(576) void k_gru(const float* __restrict__ whh, const float* __restrict__ gin,
                                             const float* __restrict__ bhh,
                                             unsigned long long* __restrict__ hbuf,
                                             float* __restrict__ hout1, float* __restrict__ hout2, int T) {
  __shared__ float h_s[2][512];
  __shared__ float gi_s[3][48];
  int g = blockIdx.x, tid = threadIdx.x, lane = tid & 63, wave = tid >> 6;
  bool iscomp = wave < 8;
  bool gl = iscomp && (lane < 2);
  int el = 2 * wave + lane;      // local element [0,16) for gate lanes
  int ge = g * 16 + el;          // global h index for gate lanes

  // register-resident W_hh slice, spread columns: w[i][j] = row i, col j*64+lane
  float w[6][8];
  if (iscomp) {
#pragma unroll
    for (int i = 0; i < 6; i++) {
      int row = (i >> 1) * HD + g * 16 + 2 * wave + (i & 1);
#pragma unroll
      for (int j = 0; j < 8; j++) w[i][j] = whh[(long)row * HD + j * 64 + lane];
    }
  }
  float bh_r = 0.f, bh_z = 0.f, bh_n = 0.f;
  if (gl) { bh_r = bhh[ge]; bh_z = bhh[HD + ge]; bh_n = bhh[2 * HD + ge]; }

  // helper preloads gi(0)
  if (wave == 8 && lane < 48)
    gi_s[0][lane] = gin[(lane >> 4) * HD + g * 16 + (lane & 15)];

  int cur = 0;   // t % 3 (hbuf rotation)
  int gb = 0;    // t % 3 (gi_s rotation)
  for (int t = 0; t < T; ++t) {
    int nxt = (cur == 2) ? 0 : cur + 1;
    int gbn = (gb == 2) ? 0 : gb + 1;
    int buf = t & 1;
    if (iscomp) {
      // pipelined poll: one slot per thread, 2 loads in flight
      unsigned long long* sp = hbuf + (long)cur * 512 + tid;
      unsigned long long a = __hip_atomic_load(sp, __ATOMIC_RELAXED, __HIP_MEMORY_SCOPE_AGENT);
      unsigned long long v;
      for (;;) {
        unsigned long long b = __hip_atomic_load(sp, __ATOMIC_RELAXED, __HIP_MEMORY_SCOPE_AGENT);
        if ((unsigned)(a >> 32) == (unsigned)t) { v = a; break; }
        a = __hip_atomic_load(sp, __ATOMIC_RELAXED, __HIP_MEMORY_SCOPE_AGENT);
        if ((unsigned)(b >> 32) == (unsigned)t) { v = b; break; }
      }
      h_s[buf][tid] = __uint_as_float((unsigned)v);
    } else if (lane < 48 && t + 1 < T) {
      gi_s[gbn][lane] = gin[(long)(t + 1) * G3H + (lane >> 4) * HD + g * 16 + (lane & 15)];
    }
    __syncthreads();

    if (iscomp) {
      float hv[8];
#pragma unroll
      for (int j = 0; j < 8; j++) hv[j] = h_s[buf][j * 64 + lane];
      float dd[6];
#pragma unroll
      for (int i = 0; i < 6; i++) {
        float d = 0.f;
#pragma unroll
        for (int j = 0; j < 8; j++) d += w[i][j] * hv[j];
#pragma unroll
        for (int o = 32; o; o >>= 1) d += __shfl_xor(d, o);
        dd[i] = d;
      }
      if (gl) {
        float dr = lane ? dd[1] : dd[0];
        float dz = lane ? dd[3] : dd[2];
        float dn = lane ? dd[5] : dd[4];
        float hp = h_s[buf][ge];   // h_s[buf][i] holds global element i
        float r  = fsigmoid(gi_s[gb][el] + dr + bh_r);
        float zz = fsigmoid(gi_s[gb][16 + el] + dz + bh_z);
        float nn = ftanh(gi_s[gb][32 + el] + r * (dn + bh_n));
        float hn = (1.f - zz) * nn + zz * hp;
        unsigned long long pk = ((unsigned long long)(unsigned)(t + 1) << 32) |
                                (unsigned long long)__float_as_uint(hn);
        __hip_atomic_store(&hbuf[(long)nxt * 512 + ge], pk,
                           __ATOMIC_RELAXED, __HIP_MEMORY_SCOPE_AGENT);
        if (t == T - 1) { hout1[ge] = hn; hout2[ge] = hn; }
      }
    }
    cur = nxt;
    gb = gbn;
  }
}

// ---------------- logits = h @ W_out + b_out ----------------
__global__ __launch_bounds__(256) void k_logits(const float* __restrict__ h, const float* __restrict__ Wout,
                                                const float* __restrict__ bout, float* __restrict__ logits) {
  __shared__ float hs[512];
  int tid = threadIdx.x;
  hs[tid] = h[tid];
  hs[tid + 256] = h[tid + 256];
  __syncthreads();
  int n = blockIdx.x * 256 + tid;
  const float* wp = Wout + n;
  float a0 = 0.f, a1 = 0.f, a2 = 0.f, a3 = 0.f;
#pragma unroll 4
  for (int k = 0; k < 512; k += 4) {
    a0 += hs[k] * wp[(long)k * VOCAB];
    a1 += hs[k + 1] * wp[(long)(k + 1) * VOCAB];
    a2 += hs[k + 2] * wp[(long)(k + 2) * VOCAB];
    a3 += hs[k + 3] * wp[(long)(k + 3) * VOCAB];
  }
  logits[n] = a0 + a1 + a2 + a3 + bout[n];
}

// ---------------- log_softmax over 32000 ----------------
__global__ __launch_bounds__(1024) void k_lsm(const float* __restrict__ logits, float* __restrict__ out) {
  __shared__ float red[16];
  int tid = threadIdx.x, lane = tid & 63, wv = tid >> 6;
  float mx = -1e30f;
  for (int i = tid; i < VOCAB; i += 1024) mx = fmaxf(mx, logits[i]);
#pragma unroll
  for (int o = 32; o; o >>= 1) mx = fmaxf(mx, __shfl_xor(mx, o));
  if (lane == 0) red[wv] = mx;
  __syncthreads();
  float M = red[0];
#pragma unroll
  for (int i = 1; i < 16; i++) M = fmaxf(M, red[i]);
  __syncthreads();
  float s = 0.f;
  for (int i = tid; i < VOCAB; i += 1024) s += expf(logits[i] - M);
#pragma unroll
  for (int o = 32; o; o >>= 1) s += __shfl_xor(s, o);
  if (lane == 0) red[wv] = s;
  __syncthreads();
  float S = 0.f;
#pragma unroll
  for (int i = 0; i < 16; i++) S += red[i];
  float lse = M + logf(S);
  for (int i = tid; i < VOCAB; i += 1024) out[i] = logits[i] - lse;
}

extern "C" void kernel_launch(void* const* d_in, const int* in_sizes, int n_in,
                              void* d_out, int out_size, void* d_ws, size_t ws_size,
                              hipStream_t stream) {
  (void)in_sizes; (void)n_in; (void)out_size; (void)ws_size;
  const int*   tok     = (const int*)d_in[0];
  const float* dec_hid = (const float*)d_in[1];
  const float* emb     = (const float*)d_in[2];
  const float* Wq      = (const float*)d_in[3];
  const float* bq      = (const float*)d_in[4];
  const float* Wk      = (const float*)d_in[5];
  const float* bk      = (const float*)d_in[6];
  const float* Wv      = (const float*)d_in[7];
  const float* bv      = (const float*)d_in[8];
  const float* Wo      = (const float*)d_in[9];
  const float* bo      = (const float*)d_in[10];
  const float* gamma   = (const float*)d_in[11];
  const float* beta    = (const float*)d_in[12];
  const float* W_ih    = (const float*)d_in[13];
  const float* W_hh    = (const float*)d_in[14];
  const float* b_ih    = (const float*)d_in[15];
  const float* b_hh    = (const float*)d_in[16];
  const float* W_out   = (const float*)d_in[17];
  const float* b_out   = (const float*)d_in[18];
  float* out = (float*)d_out;

  char* p = (char*)d_ws;
  float* xf   = (float*)p;  p += (size_t)SEQ * HD * 4;
  short* xb   = (short*)p;  p += (size_t)SEQ * HD * 2;
  short* wqkv = (short*)p;  p += (size_t)18 * HD * HD * 2;
  short* wot  = (short*)p;  p += (size_t)HD * (NHD * HD) * 2;
  short* wihb = (short*)p;  p += (size_t)G3H * HD * 2;
  short* Qb   = (short*)p;  p += (size_t)NHD * SEQ * HD * 2;
  short* Kb   = (short*)p;  p += (size_t)NHD * SEQ * HD * 2;
  short* Vt   = (short*)p;  p += (size_t)NHD * SEQ * HD * 2;
  short* Sb   = (short*)p;  p += (size_t)NHD * SEQ * SEQ * 2;
  short* catb = (short*)p;  p += (size_t)SEQ * (NHD * HD) * 2;
  float* y    = (float*)p;  p += (size_t)SEQ * HD * 4;
  short* x2b  = (short*)p;  p += (size_t)SEQ * HD * 2;
  float* gi   = (float*)p;  p += (size_t)SEQ * G3H * 4;
  unsigned long long* hbuf = (unsigned long long*)p; p += (size_t)3 * 512 * 8;
  float* hlast  = (float*)p; p += (size_t)512 * 4;
  float* logits = (float*)p; p += (size_t)VOCAB * 4;

  k_embed<<<SEQ, 128, 0, stream>>>(tok, emb, xf, xb);
  k_transp<<<dim3(8, 8, 6), 256, 0, stream>>>(Wq, wqkv, HD, HD);
  k_transp<<<dim3(8, 8, 6), 256, 0, stream>>>(Wk, wqkv + (size_t)6 * HD * HD, HD, HD);
  k_transp<<<dim3(8, 8, 6), 256, 0, stream>>>(Wv, wqkv + (size_t)12 * HD * HD, HD, HD);
  k_transp<<<dim3(8, 48, 1), 256, 0, stream>>>(Wo, wot, NHD * HD, HD);
  k_conv<<<768, 256, 0, stream>>>(W_ih, wihb);

  k_qkv<<<dim3(16, 4, 18), 256, 0, stream>>>(xb, wqkv, bq, bk, bv, Qb, Kb, Vt);
  k_scores<<<dim3(16, 16, 6), 256, 0, stream>>>(Qb, Kb, Sb);
  k_softmax<<<NHD * SEQ, 256, 0, stream>>>(Sb);
  k_pv<<<dim3(16, 4, 6), 256, 0, stream>>>(Sb, Vt, catb);
  k_oproj<<<dim3(16, 4, 1), 256, 0, stream>>>(catb, wot, bo, xf, y);
  k_ln<<<SEQ, 256, 0, stream>>>(y, gamma, beta, x2b);
  k_gi<<<dim3(16, 12, 1), 256, 0, stream>>>(x2b, wihb, b_ih, gi);

  k_gruinit<<<1, 512, 0, stream>>>(dec_hid, hbuf);
  k_gru<<<32, 576, 0, stream>>>(W_hh, gi, b_hh, hbuf, out + VOCAB, hlast, SEQ);

  k_logits<<<VOCAB / 256, 256, 0, stream>>>(hlast, W_out, b_out, logits);
  k_lsm<<<1, 1024, 0, stream>>>(logits, out);
}

// Round 5
// 4340.501 us; speedup vs baseline: 1.5222x; 1.5222x over previous
//
#include <hip/hip_runtime.h>
#include <math.h>
#include <stdint.h>

#define SEQ 2048
#define HD 512
#define NHD 6
#define VOCAB 32000
#define G3H 1536

typedef __attribute__((ext_vector_type(8))) short bf8_t;
typedef __attribute__((ext_vector_type(4))) float f4_t;

__device__ __forceinline__ short f2bf(float f) {
  union { float f; unsigned u; } x; x.f = f;
  return (short)((x.u + 0x7fffu + ((x.u >> 16) & 1u)) >> 16);
}
__device__ __forceinline__ float bf2f(short b) {
  union { unsigned u; float f; } x; x.u = ((unsigned)(unsigned short)b) << 16;
  return x.f;
}
__device__ __forceinline__ void async16(void* lds, const void* g) {
  __builtin_amdgcn_global_load_lds((__attribute__((address_space(1))) void*)g,
                                   (__attribute__((address_space(3))) void*)lds, 16, 0, 0);
}
__device__ __forceinline__ float fsigmoid(float x) {
  return 1.f / (1.f + __expf(-x));
}
__device__ __forceinline__ float ftanh(float x) {
  return 1.f - 2.f / (__expf(2.f * x) + 1.f);
}

// ---------------- core 128x128 bf16 MFMA tile GEMM (m97 structure) ----------
__device__ __forceinline__ void gemm_core(const short* __restrict__ A,
                                          const short* __restrict__ Bt,
                                          int K, int m0, int n0,
                                          f4_t acc[4][4],
                                          short* As, short* Bs) {
  int tid = threadIdx.x;
  int lane = tid & 63, wave = tid >> 6;
  int wm = (wave >> 1) * 64, wn = (wave & 1) * 64;
  int srow = lane >> 2, scol = (lane & 3) * 8;
  const short* ag0 = A + (long)(m0 + wave * 32 + srow) * K + scol;
  const short* ag1 = ag0 + 16 * (long)K;
  const short* bg0 = Bt + (long)(n0 + wave * 32 + srow) * K + scol;
  const short* bg1 = bg0 + 16 * (long)K;
  short* al0 = As + wave * 1024;
  short* al1 = As + wave * 1024 + 512;
  short* bl0 = Bs + wave * 1024;
  short* bl1 = Bs + wave * 1024 + 512;
  int fr = lane & 15, fq = lane >> 4;
  const short* afp = As + (wm + fr) * 32 + fq * 8;
  const short* bfp = Bs + (wn + fr) * 32 + fq * 8;
#pragma unroll
  for (int i = 0; i < 4; i++)
#pragma unroll
    for (int j = 0; j < 4; j++) { f4_t z = {0.f, 0.f, 0.f, 0.f}; acc[i][j] = z; }

  for (int k0 = 0; k0 < K; k0 += 32) {
    __syncthreads();
    async16(al0, ag0 + k0);
    async16(al1, ag1 + k0);
    async16(bl0, bg0 + k0);
    async16(bl1, bg1 + k0);
    __syncthreads();
    bf8_t af[4], bf[4];
#pragma unroll
    for (int mi = 0; mi < 4; mi++) af[mi] = *(const bf8_t*)(afp + mi * 512);
#pragma unroll
    for (int ni = 0; ni < 4; ni++) bf[ni] = *(const bf8_t*)(bfp + ni * 512);
#pragma unroll
    for (int mi = 0; mi < 4; mi++)
#pragma unroll
      for (int ni = 0; ni < 4; ni++)
        acc[mi][ni] = __builtin_amdgcn_mfma_f32_16x16x32_bf16(af[mi], bf[ni], acc[mi][ni], 0, 0, 0);
  }
}

// ---------------- embedding gather ----------------
__global__ __launch_bounds__(128) void k_embed(const int* __restrict__ tok, const float* __restrict__ emb,
                                               float* __restrict__ xf, short* __restrict__ xb) {
  int s = blockIdx.x;
  int t = tok[s];
  int c = threadIdx.x * 4;
  float4 v = *(const float4*)(emb + (long)t * HD + c);
  *(float4*)(xf + (long)s * HD + c) = v;
  unsigned p0 = ((unsigned)(unsigned short)f2bf(v.y) << 16) | (unsigned short)f2bf(v.x);
  unsigned p1 = ((unsigned)(unsigned short)f2bf(v.w) << 16) | (unsigned short)f2bf(v.z);
  *(uint2*)(xb + (long)s * HD + c) = make_uint2(p0, p1);
}

// ---------------- fp32 -> bf16 transpose (RxC -> CxR) ----------------
__global__ __launch_bounds__(256) void k_transp(const float* __restrict__ src, short* __restrict__ dst,
                                                int R, int C) {
  __shared__ float tile[64][65];
  const float* s = src + (long)blockIdx.z * R * C;
  short* d = dst + (long)blockIdx.z * R * C;
  int bx = blockIdx.x, by = blockIdx.y;
  int tc = threadIdx.x & 63, tr4 = threadIdx.x >> 6;
#pragma unroll
  for (int i = 0; i < 16; i++) {
    int r = tr4 + i * 4;
    tile[r][tc] = s[(long)(by * 64 + r) * C + bx * 64 + tc];
  }
  __syncthreads();
#pragma unroll
  for (int i = 0; i < 16; i++) {
    int r = tr4 + i * 4;
    d[(long)(bx * 64 + r) * R + by * 64 + tc] = f2bf(tile[tc][r]);
  }
}

// ---------------- fp32 -> bf16 convert (no transpose) ----------------
__global__ __launch_bounds__(256) void k_conv(const float* __restrict__ src, short* __restrict__ dst) {
  long i = (long)(blockIdx.x * 256 + threadIdx.x) * 4;
  float4 v = *(const float4*)(src + i);
  unsigned p0 = ((unsigned)(unsigned short)f2bf(v.y) << 16) | (unsigned short)f2bf(v.x);
  unsigned p1 = ((unsigned)(unsigned short)f2bf(v.w) << 16) | (unsigned short)f2bf(v.z);
  *(uint2*)(dst + i) = make_uint2(p0, p1);
}

// ---------------- QKV projections (18 batched GEMMs) ----------------
__global__ __launch_bounds__(256) void k_qkv(const short* __restrict__ xb, const short* __restrict__ wt,
                                             const float* __restrict__ bq, const float* __restrict__ bk,
                                             const float* __restrict__ bv,
                                             short* __restrict__ Qb, short* __restrict__ Kb,
                                             short* __restrict__ Vt) {
  __shared__ short As[4096], Bs[4096];
  int z = blockIdx.z, which = z / 6, h = z % 6;
  int m0 = blockIdx.x * 128, n0 = blockIdx.y * 128;
  f4_t acc[4][4];
  gemm_core(xb, wt + (long)z * HD * HD, HD, m0, n0, acc, As, Bs);
  int lane = threadIdx.x & 63, wave = threadIdx.x >> 6;
  int wm = (wave >> 1) * 64, wn = (wave & 1) * 64;
  int fr = lane & 15, fq = lane >> 4;
  const float* bias = (which == 0) ? bq : (which == 1) ? bk : bv;
  short* qk = (which == 0) ? Qb : Kb;
#pragma unroll
  for (int mi = 0; mi < 4; mi++)
#pragma unroll
    for (int ni = 0; ni < 4; ni++) {
      int n = n0 + wn + ni * 16 + fr;
      float b = bias[h * HD + n];
#pragma unroll
      for (int r = 0; r < 4; r++) {
        int m = m0 + wm + mi * 16 + fq * 4 + r;
        float v = acc[mi][ni][r] + b;
        if (which < 2) qk[(long)h * SEQ * HD + (long)m * HD + n] = f2bf(v);
        else           Vt[(long)h * HD * SEQ + (long)n * SEQ + m] = f2bf(v);
      }
    }
}

// ---------------- scores = Q K^T / sqrt(H) ----------------
__global__ __launch_bounds__(256) void k_scores(const short* __restrict__ Qb, const short* __restrict__ Kb,
                                                short* __restrict__ Sb) {
  __shared__ short As[4096], Bs[4096];
  int h = blockIdx.z;
  int m0 = blockIdx.x * 128, n0 = blockIdx.y * 128;
  f4_t acc[4][4];
  gemm_core(Qb + (long)h * SEQ * HD, Kb + (long)h * SEQ * HD, HD, m0, n0, acc, As, Bs);
  int lane = threadIdx.x & 63, wave = threadIdx.x >> 6;
  int wm = (wave >> 1) * 64, wn = (wave & 1) * 64;
  int fr = lane & 15, fq = lane >> 4;
  const float sc = 0.04419417382415922f;  // 1/sqrt(512)
#pragma unroll
  for (int mi = 0; mi < 4; mi++)
#pragma unroll
    for (int ni = 0; ni < 4; ni++) {
      int n = n0 + wn + ni * 16 + fr;
#pragma unroll
      for (int r = 0; r < 4; r++) {
        int m = m0 + wm + mi * 16 + fq * 4 + r;
        Sb[(long)h * SEQ * SEQ + (long)m * SEQ + n] = f2bf(acc[mi][ni][r] * sc);
      }
    }
}

// ---------------- row softmax (in-place, bf16) ----------------
__global__ __launch_bounds__(256) void k_softmax(short* __restrict__ S) {
  __shared__ float red[4];
  short* p = S + (long)blockIdx.x * SEQ;
  int tid = threadIdx.x, lane = tid & 63, wv = tid >> 6;
  bf8_t raw = *(const bf8_t*)(p + tid * 8);
  float v[8];
#pragma unroll
  for (int i = 0; i < 8; i++) v[i] = bf2f(raw[i]);
  float mx = v[0];
#pragma unroll
  for (int i = 1; i < 8; i++) mx = fmaxf(mx, v[i]);
#pragma unroll
  for (int o = 32; o; o >>= 1) mx = fmaxf(mx, __shfl_xor(mx, o));
  if (lane == 0) red[wv] = mx;
  __syncthreads();
  float M = fmaxf(fmaxf(red[0], red[1]), fmaxf(red[2], red[3]));
  __syncthreads();
  float e[8], s = 0.f;
#pragma unroll
  for (int i = 0; i < 8; i++) { e[i] = expf(v[i] - M); s += e[i]; }
#pragma unroll
  for (int o = 32; o; o >>= 1) s += __shfl_xor(s, o);
  if (lane == 0) red[wv] = s;
  __syncthreads();
  float inv = 1.f / (red[0] + red[1] + red[2] + red[3]);
  bf8_t o8;
#pragma unroll
  for (int i = 0; i < 8; i++) o8[i] = f2bf(e[i] * inv);
  *(bf8_t*)(p + tid * 8) = o8;
}

// ---------------- heads = P V, written into cat layout ----------------
__global__ __launch_bounds__(256) void k_pv(const short* __restrict__ Sb, const short* __restrict__ Vt,
                                            short* __restrict__ cat) {
  __shared__ short As[4096], Bs[4096];
  int h = blockIdx.z;
  int m0 = blockIdx.x * 128, n0 = blockIdx.y * 128;
  f4_t acc[4][4];
  gemm_core(Sb + (long)h * SEQ * SEQ, Vt + (long)h * HD * SEQ, SEQ, m0, n0, acc, As, Bs);
  int lane = threadIdx.x & 63, wave = threadIdx.x >> 6;
  int wm = (wave >> 1) * 64, wn = (wave & 1) * 64;
  int fr = lane & 15, fq = lane >> 4;
#pragma unroll
  for (int mi = 0; mi < 4; mi++)
#pragma unroll
    for (int ni = 0; ni < 4; ni++) {
      int n = n0 + wn + ni * 16 + fr;
#pragma unroll
      for (int r = 0; r < 4; r++) {
        int m = m0 + wm + mi * 16 + fq * 4 + r;
        cat[(long)m * (NHD * HD) + h * HD + n] = f2bf(acc[mi][ni][r]);
      }
    }
}

// ---------------- out proj + residual: y = x + cat@Wo + bo ----------------
__global__ __launch_bounds__(256) void k_oproj(const short* __restrict__ cat, const short* __restrict__ wot,
                                               const float* __restrict__ bo, const float* __restrict__ xf,
                                               float* __restrict__ y) {
  __shared__ short As[4096], Bs[4096];
  int m0 = blockIdx.x * 128, n0 = blockIdx.y * 128;
  f4_t acc[4][4];
  gemm_core(cat, wot, NHD * HD, m0, n0, acc, As, Bs);
  int lane = threadIdx.x & 63, wave = threadIdx.x >> 6;
  int wm = (wave >> 1) * 64, wn = (wave & 1) * 64;
  int fr = lane & 15, fq = lane >> 4;
#pragma unroll
  for (int mi = 0; mi < 4; mi++)
#pragma unroll
    for (int ni = 0; ni < 4; ni++) {
      int n = n0 + wn + ni * 16 + fr;
      float b = bo[n];
#pragma unroll
      for (int r = 0; r < 4; r++) {
        int m = m0 + wm + mi * 16 + fq * 4 + r;
        y[(long)m * HD + n] = acc[mi][ni][r] + b + xf[(long)m * HD + n];
      }
    }
}

// ---------------- LayerNorm ----------------
__global__ __launch_bounds__(256) void k_ln(const float* __restrict__ y, const float* __restrict__ gamma,
                                            const float* __restrict__ beta, short* __restrict__ x2b) {
  __shared__ float red[8];
  int r = blockIdx.x, tid = threadIdx.x, lane = tid & 63, wv = tid >> 6;
  float2 v = *(const float2*)(y + (long)r * HD + tid * 2);
  float s = v.x + v.y, q = v.x * v.x + v.y * v.y;
#pragma unroll
  for (int o = 32; o; o >>= 1) { s += __shfl_xor(s, o); q += __shfl_xor(q, o); }
  if (lane == 0) { red[wv] = s; red[4 + wv] = q; }
  __syncthreads();
  float S = red[0] + red[1] + red[2] + red[3];
  float Q = red[4] + red[5] + red[6] + red[7];
  float mu = S / 512.f, var = Q / 512.f - mu * mu;
  float rs = rsqrtf(var + 1e-5f);
  int c = tid * 2;
  float o0 = (v.x - mu) * rs * gamma[c] + beta[c];
  float o1 = (v.y - mu) * rs * gamma[c + 1] + beta[c + 1];
  unsigned pk = ((unsigned)(unsigned short)f2bf(o1) << 16) | (unsigned short)f2bf(o0);
  *(unsigned*)(x2b + (long)r * HD + c) = pk;
}

// ---------------- gi = x2 @ W_ih^T + b_ih (fp32 out) ----------------
__global__ __launch_bounds__(256) void k_gi(const short* __restrict__ x2b, const short* __restrict__ wihb,
                                            const float* __restrict__ bih, float* __restrict__ gi) {
  __shared__ short As[4096], Bs[4096];
  int m0 = blockIdx.x * 128, n0 = blockIdx.y * 128;
  f4_t acc[4][4];
  gemm_core(x2b, wihb, HD, m0, n0, acc, As, Bs);
  int lane = threadIdx.x & 63, wave = threadIdx.x >> 6;
  int wm = (wave >> 1) * 64, wn = (wave & 1) * 64;
  int fr = lane & 15, fq = lane >> 4;
#pragma unroll
  for (int mi = 0; mi < 4; mi++)
#pragma unroll
    for (int ni = 0; ni < 4; ni++) {
      int n = n0 + wn + ni * 16 + fr;
      float b = bih[n];
#pragma unroll
      for (int r = 0; r < 4; r++) {
        int m = m0 + wm + mi * 16 + fq * 4 + r;
        gi[(long)m * G3H + n] = acc[mi][ni][r] + b;
      }
    }
}

// ---------------- GRU init: pack h0 with tag 0 ----------------
__global__ __launch_bounds__(512) void k_gruinit(const float* __restrict__ h0,
                                                 unsigned long long* __restrict__ hbuf) {
  int i = threadIdx.x;
  hbuf[i] = (unsigned long long)__float_as_uint(h0[i]);  // tag 0 in hi32
  hbuf[512 + i] = 0xFFFFFFFF00000000ULL;
  hbuf[1024 + i] = 0xFFFFFFFF00000000ULL;
}

// ---------------- GRU scan: 64 blocks x 512, single-poller-wave exchange ---
// Block g owns h elements [8g, 8g+8), i.e. 24 W_hh rows (3 gates x 8 elems),
// 3 rows per wave (w[3][8] regs, spread columns). Per step:
//   wave0: polls ALL 512 slots (8/lane, pipelined 8B atomic loads, __all vote)
//          -> writes h to LDS.  Other waves wait in barrier (no mem traffic!).
//   B1; all 8 waves: dd[i] = row-dot + butterfly; lanes 0-2 write gh_s.
//       wave1 also issues gi(t+1) global loads (async, consumed post-B2).
//   B2; wave0 lanes 0-7: gates for all 8 elements; ONE 64B single-line burst
//       of tagged stores. wave1: ds_write gi_s[(t+1)%3] (depth-3 rotation).
// Rationale vs r4: poll flood congested the coherence point and queued the
// producer stores behind it; single-wave polling cuts poll traffic ~30x and
// the burst store makes each block's contribution one line.
__global__ __launch_bounds__(512) void k_gru(const float* __restrict__ whh, const float* __restrict__ gin,
                                             const float* __restrict__ bhh,
                                             unsigned long long* __restrict__ hbuf,
                                             float* __restrict__ hout1, float* __restrict__ hout2, int T) {
  __shared__ float h_s[512];
  __shared__ float gh_s[24];
  __shared__ float gi_s[3][24];
  int g = blockIdx.x, tid = threadIdx.x, lane = tid & 63, wave = tid >> 6;

  // weights: wave w covers rows ri = 3w..3w+2; ri -> gate ty=ri>>3, elem e=ri&7
  float w[3][8];
#pragma unroll
  for (int i = 0; i < 3; i++) {
    int ri = wave * 3 + i;
    int row = (ri >> 3) * HD + g * 8 + (ri & 7);
#pragma unroll
    for (int j = 0; j < 8; j++) w[i][j] = whh[(long)row * HD + j * 64 + lane];
  }
  float bh_r = 0.f, bh_z = 0.f, bh_n = 0.f;
  if (wave == 0 && lane < 8) {
    int ge = g * 8 + lane;
    bh_r = bhh[ge]; bh_z = bhh[HD + ge]; bh_n = bhh[2 * HD + ge];
  }
  // wave1 preloads gi(0)
  if (wave == 1 && lane < 24)
    gi_s[0][lane] = gin[(lane >> 3) * HD + g * 8 + (lane & 7)];

  int cur = 0, gb = 0;
  for (int t = 0; t < T; ++t) {
    int nxt = (cur == 2) ? 0 : cur + 1;
    int gbn = (gb == 2) ? 0 : gb + 1;

    float ngi[3];
    if (wave == 0) {
      // poll 8 slots per lane until all carry tag t
      unsigned long long* sp = hbuf + (long)cur * 512 + lane * 8;
      unsigned long long v[8];
      for (;;) {
        bool ok = true;
#pragma unroll
        for (int k = 0; k < 8; k++)
          v[k] = __hip_atomic_load(sp + k, __ATOMIC_RELAXED, __HIP_MEMORY_SCOPE_AGENT);
#pragma unroll
        for (int k = 0; k < 8; k++) ok &= ((unsigned)(v[k] >> 32) == (unsigned)t);
        if (__all(ok)) break;
      }
      float hv8[8];
#pragma unroll
      for (int k = 0; k < 8; k++) hv8[k] = __uint_as_float((unsigned)v[k]);
      *(float4*)&h_s[lane * 8]     = make_float4(hv8[0], hv8[1], hv8[2], hv8[3]);
      *(float4*)&h_s[lane * 8 + 4] = make_float4(hv8[4], hv8[5], hv8[6], hv8[7]);
    } else if (wave == 1 && lane < 24 && t + 1 < T) {
      // async issue; ds_write after B2
      ngi[0] = gin[(long)(t + 1) * G3H + (lane >> 3) * HD + g * 8 + (lane & 7)];
    }
    __syncthreads();  // B1: h_s ready

    float hv[8];
#pragma unroll
    for (int j = 0; j < 8; j++) hv[j] = h_s[j * 64 + lane];
    float dd[3];
#pragma unroll
    for (int i = 0; i < 3; i++) {
      float d = 0.f;
#pragma unroll
      for (int j = 0; j < 8; j++) d += w[i][j] * hv[j];
#pragma unroll
      for (int o = 32; o; o >>= 1) d += __shfl_xor(d, o);
      dd[i] = d;
    }
    if (lane < 3) gh_s[wave * 3 + lane] = dd[lane];
    __syncthreads();  // B2: gh_s ready

    if (wave == 0 && lane < 8) {
      int e = lane, ge = g * 8 + e;
      float dr = gh_s[e], dz = gh_s[8 + e], dn = gh_s[16 + e];
      float hp = h_s[ge & 511];
      float r  = fsigmoid(gi_s[gb][e] + dr + bh_r);
      float zz = fsigmoid(gi_s[gb][8 + e] + dz + bh_z);
      float nn = ftanh(gi_s[gb][16 + e] + r * (dn + bh_n));
      float hn = (1.f - zz) * nn + zz * hp;
      unsigned long long pk = ((unsigned long long)(unsigned)(t + 1) << 32) |
                              (unsigned long long)__float_as_uint(hn);
      __hip_atomic_store(&hbuf[(long)nxt * 512 + ge], pk,
                         __ATOMIC_RELAXED, __HIP_MEMORY_SCOPE_AGENT);
      if (t == T - 1) { hout1[ge] = hn; hout2[ge] = hn; }
    } else if (wave == 1 && lane < 24 && t + 1 < T) {
      gi_s[gbn][lane] = ngi[0];
    }
    cur = nxt;
    gb = gbn;
  }
}

// ---------------- logits = h @ W_out + b_out ----------------
__global__ __launch_bounds__(256) void k_logits(const float* __restrict__ h, const float* __restrict__ Wout,
                                                const float* __restrict__ bout, float* __restrict__ logits) {
  __shared__ float hs[512];
  int tid = threadIdx.x;
  hs[tid] = h[tid];
  hs[tid + 256] = h[tid + 256];
  __syncthreads();
  int n = blockIdx.x * 256 + tid;
  const float* wp = Wout + n;
  float a0 = 0.f, a1 = 0.f, a2 = 0.f, a3 = 0.f;
#pragma unroll 4
  for (int k = 0; k < 512; k += 4) {
    a0 += hs[k] * wp[(long)k * VOCAB];
    a1 += hs[k + 1] * wp[(long)(k + 1) * VOCAB];
    a2 += hs[k + 2] * wp[(long)(k + 2) * VOCAB];
    a3 += hs[k + 3] * wp[(long)(k + 3) * VOCAB];
  }
  logits[n] = a0 + a1 + a2 + a3 + bout[n];
}

// ---------------- log_softmax over 32000 ----------------
__global__ __launch_bounds__(1024) void k_lsm(const float* __restrict__ logits, float* __restrict__ out) {
  __shared__ float red[16];
  int tid = threadIdx.x, lane = tid & 63, wv = tid >> 6;
  float mx = -1e30f;
  for (int i = tid; i < VOCAB; i += 1024) mx = fmaxf(mx, logits[i]);
#pragma unroll
  for (int o = 32; o; o >>= 1) mx = fmaxf(mx, __shfl_xor(mx, o));
  if (lane == 0) red[wv] = mx;
  __syncthreads();
  float M = red[0];
#pragma unroll
  for (int i = 1; i < 16; i++) M = fmaxf(M, red[i]);
  __syncthreads();
  float s = 0.f;
  for (int i = tid; i < VOCAB; i += 1024) s += expf(logits[i] - M);
#pragma unroll
  for (int o = 32; o; o >>= 1) s += __shfl_xor(s, o);
  if (lane == 0) red[wv] = s;
  __syncthreads();
  float S = 0.f;
#pragma unroll
  for (int i = 0; i < 16; i++) S += red[i];
  float lse = M + logf(S);
  for (int i = tid; i < VOCAB; i += 1024) out[i] = logits[i] - lse;
}

extern "C" void kernel_launch(void* const* d_in, const int* in_sizes, int n_in,
                              void* d_out, int out_size, void* d_ws, size_t ws_size,
                              hipStream_t stream) {
  (void)in_sizes; (void)n_in; (void)out_size; (void)ws_size;
  const int*   tok     = (const int*)d_in[0];
  const float* dec_hid = (const float*)d_in[1];
  const float* emb     = (const float*)d_in[2];
  const float* Wq      = (const float*)d_in[3];
  const float* bq      = (const float*)d_in[4];
  const float* Wk      = (const float*)d_in[5];
  const float* bk      = (const float*)d_in[6];
  const float* Wv      = (const float*)d_in[7];
  const float* bv      = (const float*)d_in[8];
  const float* Wo      = (const float*)d_in[9];
  const float* bo      = (const float*)d_in[10];
  const float* gamma   = (const float*)d_in[11];
  const float* beta    = (const float*)d_in[12];
  const float* W_ih    = (const float*)d_in[13];
  const float* W_hh    = (const float*)d_in[14];
  const float* b_ih    = (const float*)d_in[15];
  const float* b_hh    = (const float*)d_in[16];
  const float* W_out   = (const float*)d_in[17];
  const float* b_out   = (const float*)d_in[18];
  float* out = (float*)d_out;

  char* p = (char*)d_ws;
  float* xf   = (float*)p;  p += (size_t)SEQ * HD * 4;
  short* xb   = (short*)p;  p += (size_t)SEQ * HD * 2;
  short* wqkv = (short*)p;  p += (size_t)18 * HD * HD * 2;
  short* wot  = (short*)p;  p += (size_t)HD * (NHD * HD) * 2;
  short* wihb = (short*)p;  p += (size_t)G3H * HD * 2;
  short* Qb   = (short*)p;  p += (size_t)NHD * SEQ * HD * 2;
  short* Kb   = (short*)p;  p += (size_t)NHD * SEQ * HD * 2;
  short* Vt   = (short*)p;  p += (size_t)NHD * SEQ * HD * 2;
  short* Sb   = (short*)p;  p += (size_t)NHD * SEQ * SEQ * 2;
  short* catb = (short*)p;  p += (size_t)SEQ * (NHD * HD) * 2;
  float* y    = (float*)p;  p += (size_t)SEQ * HD * 4;
  short* x2b  = (short*)p;  p += (size_t)SEQ * HD * 2;
  float* gi   = (float*)p;  p += (size_t)SEQ * G3H * 4;
  unsigned long long* hbuf = (unsigned long long*)p; p += (size_t)3 * 512 * 8;
  float* hlast  = (float*)p; p += (size_t)512 * 4;
  float* logits = (float*)p; p += (size_t)VOCAB * 4;

  k_embed<<<SEQ, 128, 0, stream>>>(tok, emb, xf, xb);
  k_transp<<<dim3(8, 8, 6), 256, 0, stream>>>(Wq, wqkv, HD, HD);
  k_transp<<<dim3(8, 8, 6), 256, 0, stream>>>(Wk, wqkv + (size_t)6 * HD * HD, HD, HD);
  k_transp<<<dim3(8, 8, 6), 256, 0, stream>>>(Wv, wqkv + (size_t)12 * HD * HD, HD, HD);
  k_transp<<<dim3(8, 48, 1), 256, 0, stream>>>(Wo, wot, NHD * HD, HD);
  k_conv<<<768, 256, 0, stream>>>(W_ih, wihb);

  k_qkv<<<dim3(16, 4, 18), 256, 0, stream>>>(xb, wqkv, bq, bk, bv, Qb, Kb, Vt);
  k_scores<<<dim3(16, 16, 6), 256, 0, stream>>>(Qb, Kb, Sb);
  k_softmax<<<NHD * SEQ, 256, 0, stream>>>(Sb);
  k_pv<<<dim3(16, 4, 6), 256, 0, stream>>>(Sb, Vt, catb);
  k_oproj<<<dim3(16, 4, 1), 256, 0, stream>>>(catb, wot, bo, xf, y);
  k_ln<<<SEQ, 256, 0, stream>>>(y, gamma, beta, x2b);
  k_gi<<<dim3(16, 12, 1), 256, 0, stream>>>(x2b, wihb, b_ih, gi);

  k_gruinit<<<1, 512, 0, stream>>>(dec_hid, hbuf);
  k_gru<<<64, 512, 0, stream>>>(W_hh, gi, b_hh, hbuf, out + VOCAB, hlast, SEQ);

  k_logits<<<VOCAB / 256, 256, 0, stream>>>(hlast, W_out, b_out, logits);
  k_lsm<<<1, 1024, 0, stream>>>(logits, out);
}